// Round 9
// baseline (51.912 us; speedup 1.0000x reference)
//
#include <hip/hip_runtime.h>
#include <math.h>

#define BATCH 32
#define M 64
#define R 8
typedef unsigned long long u64;
typedef unsigned int u32;

// XOR swizzle of the float4 slot within a 64-float (256 B) LDS row (G4 recipe).
#define SWZ_SLOT(r, s) ((s) ^ ((r) & 7))
#define PM_IDX(r, c) ((((r) << 6)) + ((SWZ_SLOT((r), (c) >> 2) << 2) | ((c) & 3)))

__device__ __forceinline__ u32 umax2(u32 a, u32 b) { return a > b ? a : b; }
__device__ __forceinline__ u32 umax3(u32 a, u32 b, u32 c) {
    return umax2(umax2(a, b), c);                    // fuses to v_max3_u32
}

// Monotone f32 -> u32 map (order-preserving, total).
__device__ __forceinline__ u32 sortable(float f) {
    const u32 u = __float_as_uint(f);
    return u ^ ((u32)(((int)u) >> 31) | 0x80000000u);
}
// Inverse of sortable() (low 6 bits unknown; caller passes midpoint).
__device__ __forceinline__ float unsortable(u32 k) {
    const u32 fb = (k & 0x80000000u) ? (k ^ 0x80000000u) : ~k;
    return __uint_as_float(fb);
}

// sign-extended bit j of w: 0xFFFFFFFF if set, else 0.
#define SEXTBIT(w, j) ((u32)(((int)((w) << (31 - (j)))) >> 31))

// masked element: packed value, or 0 if column j is blocked.
#define KM(j) (p##j & SEXTBIT(((j) < 32 ? nlo : nhi), (j) & 31))

// Wave-wide u32 max: 3 max3-windowed DPP steps (16-lane rows) + 4 readlanes
// + scalar max tree. old=src, bound_ctrl=false => invalid lanes self-max.
__device__ __forceinline__ u32 wave_umax_scalar(u32 g) {
    int v = (int)g;
    const int s1a = __builtin_amdgcn_update_dpp(v, v, 0x111, 0xf, 0xf, false); // shr1
    const int s1b = __builtin_amdgcn_update_dpp(v, v, 0x112, 0xf, 0xf, false); // shr2
    const u32 t1 = umax3(g, (u32)s1a, (u32)s1b);                // window 3
    const int w = (int)t1;
    const int s2a = __builtin_amdgcn_update_dpp(w, w, 0x113, 0xf, 0xf, false); // shr3
    const int s2b = __builtin_amdgcn_update_dpp(w, w, 0x116, 0xf, 0xf, false); // shr6
    const u32 t2 = umax3(t1, (u32)s2a, (u32)s2b);               // window 9
    const int y = (int)t2;
    const int s3 = __builtin_amdgcn_update_dpp(y, y, 0x117, 0xf, 0xf, false);  // shr7
    const u32 t3 = umax2(t2, (u32)s3);                          // window 16
    const u32 a = (u32)__builtin_amdgcn_readlane((int)t3, 15);
    const u32 b = (u32)__builtin_amdgcn_readlane((int)t3, 31);
    const u32 c = (u32)__builtin_amdgcn_readlane((int)t3, 47);
    const u32 d = (u32)__builtin_amdgcn_readlane((int)t3, 63);
    return umax2(umax2(a, b), umax2(c, d));                     // scalar s_max
}

__device__ __forceinline__ u64 readlane_u64(u64 v, int lane) {
    unsigned lo = (unsigned)__builtin_amdgcn_readlane((int)(unsigned)v, lane);
    unsigned hi = (unsigned)__builtin_amdgcn_readlane((int)(v >> 32), lane);
    return ((u64)hi << 32) | lo;
}

// pack: 26-bit sortable value | (63 - col) in low 6 bits.
#define PK(f, j) ((sortable(f) | 63u) ^ (u32)(j))
// LDS float4 -> four named packed registers.
#define LOADP(s, a, b, c, d) { const float4 v_ = row4[(s) ^ x]; \
    p##a = PK(v_.x, a); p##b = PK(v_.y, b); p##c = PK(v_.z, c); p##d = PK(v_.w, d); }

#define T1(n, A, B, C2) const u32 a##n = umax3(KM(A), KM(B), KM(C2));

// Fixed-order final reduction, run by the last finishing wave (device-scope).
__device__ __forceinline__ void final_reduce(const float* mst_p, const float* ls_p,
                                             float* out) {
    __threadfence();                                 // acquire all partials
    float s = 0.0f;
    #pragma unroll
    for (int i = 0; i < BATCH; ++i) s += mst_p[i] - ls_p[i];
    out[0] = s * (1.0f / BATCH);
}

// One block per batch. 4 waves stage pairmax into LDS; wave 0 holds its row as
// 64 packed u32 registers (loop-invariant) + a cumulative not-blocked mask and
// runs the greedy loop with ZERO memory ops; wave 1 does the label score.
// The 64th finishing writer (of 32 mst + 32 ls) does the final reduction.
__global__ __launch_bounds__(256)
__attribute__((amdgpu_waves_per_eu(1, 1)))
void tree_crf_mst_kernel(const float* __restrict__ le,   // [B, M, M, R]
                         const int* __restrict__ tree,   // [B, M, 3]
                         float* __restrict__ mst_out,    // [B] (d_ws)
                         float* __restrict__ ls_out,     // [B] (d_ws)
                         u32* __restrict__ done_cnt,     // [1] (d_ws, pre-zeroed)
                         float* __restrict__ out)        // [1] (d_out)
{
    __shared__ __align__(16) float pm[M * M];            // 16 KB swizzled rows
    const int b = blockIdx.x;
    const int tt = threadIdx.x;
    const float* bl = le + (size_t)b * M * M * R;
    const float4* g4 = reinterpret_cast<const float4*>(bl);

    // ---- stage pairmax[r][c] = max_k le[r,c,k] (all 4 waves, coalesced) ----
    for (int q = tt; q < M * M; q += 256) {
        const float4 a  = g4[2 * q];
        const float4 c4 = g4[2 * q + 1];
        const float mx = fmaxf(fmaxf(fmaxf(a.x, a.y), fmaxf(a.z, a.w)),
                               fmaxf(fmaxf(c4.x, c4.y), fmaxf(c4.z, c4.w)));
        const int rr = q >> 6, cc = q & 63;
        pm[PM_IDX(rr, cc)] = mx;
    }
    __syncthreads();                                     // only barrier

    const int wave = tt >> 6;
    const int t = tt & 63;

    if (wave == 1) {
        // ---- label tree score (overlaps wave 0's greedy loop) ----
        const int* tr = tree + ((size_t)b * M + t) * 3;
        const int i0 = tr[0], i1 = tr[1], i2 = tr[2];
        float ls = 0.0f;
        if (!((i0 == 0) & (i1 == 0) & (i2 == 0)))        // (0,0,0) contributes 0
            ls = bl[(size_t)((i0 << 6) | i1) * R + i2];
        #pragma unroll
        for (int off = 32; off; off >>= 1) ls += __shfl_down(ls, off);
        if (t == 0) {
            ls_out[b] = ls;
            __threadfence();                             // release partial
            if (atomicAdd(done_cnt, 1u) == 2 * BATCH - 1)
                final_reduce(mst_out, ls_out, out);
        }
        return;
    }
    if (wave != 0) return;

    // ---- lane t: row t as 64 packed u32 named registers (loop-invariant) ----
    u32 p0,p1,p2,p3,p4,p5,p6,p7,p8,p9,p10,p11,p12,p13,p14,p15,
        p16,p17,p18,p19,p20,p21,p22,p23,p24,p25,p26,p27,p28,p29,p30,p31,
        p32,p33,p34,p35,p36,p37,p38,p39,p40,p41,p42,p43,p44,p45,p46,p47,
        p48,p49,p50,p51,p52,p53,p54,p55,p56,p57,p58,p59,p60,p61,p62,p63;
    {
        const float4* row4 = reinterpret_cast<const float4*>(pm) + (t << 4);
        const int x = t & 7;
        LOADP(0,  0,  1,  2,  3)  LOADP(1,  4,  5,  6,  7)
        LOADP(2,  8,  9,  10, 11) LOADP(3,  12, 13, 14, 15)
        LOADP(4,  16, 17, 18, 19) LOADP(5,  20, 21, 22, 23)
        LOADP(6,  24, 25, 26, 27) LOADP(7,  28, 29, 30, 31)
        LOADP(8,  32, 33, 34, 35) LOADP(9,  36, 37, 38, 39)
        LOADP(10, 40, 41, 42, 43) LOADP(11, 44, 45, 46, 47)
        LOADP(12, 48, 49, 50, 51) LOADP(13, 52, 53, 54, 55)
        LOADP(14, 56, 57, 58, 59) LOADP(15, 60, 61, 62, 63)
    }

    const u64 lanebit = 1ull << t;
    u64 mask = lanebit;                                  // partition of node t
    u32 nlo = 0xFFFFFFFFu, nhi = 0xFFFFFFFFu;            // ~blocked columns
    float mst = 0.0f;

    #pragma unroll 1                                     // keep loop rolled
    for (int it = 0; it < M; ++it) {
        // ---- masked row max: 2-op mask leaves + v_max3_u32 tree ----
        T1(0,0,1,2)    T1(1,3,4,5)    T1(2,6,7,8)    T1(3,9,10,11)
        T1(4,12,13,14) T1(5,15,16,17) T1(6,18,19,20) T1(7,21,22,23)
        T1(8,24,25,26) T1(9,27,28,29) T1(10,30,31,32) T1(11,33,34,35)
        T1(12,36,37,38) T1(13,39,40,41) T1(14,42,43,44) T1(15,45,46,47)
        T1(16,48,49,50) T1(17,51,52,53) T1(18,54,55,56) T1(19,57,58,59)
        T1(20,60,61,62)
        const u32 a21 = KM(63);
        const u32 b0 = umax3(a0,  a1,  a2);
        const u32 b1 = umax3(a3,  a4,  a5);
        const u32 b2 = umax3(a6,  a7,  a8);
        const u32 b3 = umax3(a9,  a10, a11);
        const u32 b4 = umax3(a12, a13, a14);
        const u32 b5 = umax3(a15, a16, a17);
        const u32 b6 = umax3(a18, a19, a20);
        const u32 c0 = umax3(b0, b1, b2);
        const u32 c1 = umax3(b3, b4, b5);
        const u32 c2 = umax2(b6, a21);
        const u32 rowmax = umax3(c0, c1, c2);

        // ---- global max over UNSTRIPPED keys: gj available immediately ----
        const u32 gv = wave_umax_scalar(rowmax);
        if (gv == 0u) break;                             // all blocked
        const int gj = (int)((~gv) & 63u);               // low6 = 63 - col
        const u64 mt = readlane_u64(mask, gj);           // issues early,
                                                         // parallel to ballot
        const u64 sel = __ballot(rowmax == gv);
        const int gi = __ffsll((long long)sel) - 1;      // smallest row on tie
        const u64 mf = readlane_u64(mask, gi);

        mst += unsortable((gv & 0xFFFFFFC0u) | 32u);     // mid of lost low bits

        const u64 merged = mf | mt;
        if (merged & lanebit) mask = merged;

        // ---- block P x Q and Q x P (row-t slice): cumulative bitmask only ----
        const u64 rb = ((mf & lanebit) ? mt : 0ull) | ((mt & lanebit) ? mf : 0ull);
        nlo &= ~(u32)rb;
        nhi &= ~(u32)(rb >> 32);
    }
    if (t == 0) {
        mst_out[b] = mst;
        __threadfence();                                 // release partial
        if (atomicAdd(done_cnt, 1u) == 2 * BATCH - 1)
            final_reduce(mst_out, ls_out, out);
    }
}

extern "C" void kernel_launch(void* const* d_in, const int* in_sizes, int n_in,
                              void* d_out, int out_size, void* d_ws, size_t ws_size,
                              hipStream_t stream) {
    const float* le   = (const float*)d_in[0];   // [32, 64, 64, 8] f32
    const int*   tree = (const int*)d_in[1];     // [32, 64, 3] i32
    float* out = (float*)d_out;                  // [1] f32
    float* mst_p = (float*)d_ws;                 // [32]
    float* ls_p  = mst_p + BATCH;                // [32]
    u32* done    = (u32*)(mst_p + 2 * BATCH);    // [1] completion counter

    // Zero the counter each call (stream op -> graph-capturable).
    hipMemsetAsync(done, 0, sizeof(u32), stream);
    tree_crf_mst_kernel<<<BATCH, 256, 0, stream>>>(le, tree, mst_p, ls_p,
                                                   done, out);
}

// Round 10
// 45.444 us; speedup vs baseline: 1.1423x; 1.1423x over previous
//
#include <hip/hip_runtime.h>
#include <math.h>

#define BATCH 32
#define M 64
#define R 8
typedef unsigned long long u64;
typedef unsigned int u32;

// XOR swizzle of the float4 slot within a 64-float (256 B) LDS row (G4 recipe).
#define SWZ_SLOT(r, s) ((s) ^ ((r) & 7))
#define PM_IDX(r, c) ((((r) << 6)) + ((SWZ_SLOT((r), (c) >> 2) << 2) | ((c) & 3)))

__device__ __forceinline__ u32 umax2(u32 a, u32 b) { return a > b ? a : b; }
__device__ __forceinline__ u32 umax3(u32 a, u32 b, u32 c) {
    return umax2(umax2(a, b), c);                    // fuses to v_max3_u32
}

// Monotone f32 -> u32 map (order-preserving, total).
__device__ __forceinline__ u32 sortable(float f) {
    const u32 u = __float_as_uint(f);
    return u ^ ((u32)(((int)u) >> 31) | 0x80000000u);
}
// Inverse of sortable() (low 12 bits unknown; caller passes midpoint).
__device__ __forceinline__ float unsortable(u32 k) {
    const u32 fb = (k & 0x80000000u) ? (k ^ 0x80000000u) : ~k;
    return __uint_as_float(fb);
}

// sign-extended bit j of w: 0xFFFFFFFF if set, else 0 (v_bfe_i32).
#define SEXTBIT(w, j) ((u32)(((int)((w) << (31 - (j)))) >> 31))

// masked element: packed key, or 0 if column j is blocked.
#define KM(j) (p##j & SEXTBIT(((j) < 32 ? nlo : nhi), (j) & 31))

// Wave-wide u32 max: 3 max3-windowed DPP steps (16-lane rows) + 4 readlanes
// + scalar max tree. old=src, bound_ctrl=false => invalid lanes self-max.
__device__ __forceinline__ u32 wave_umax_scalar(u32 g) {
    int v = (int)g;
    const int s1a = __builtin_amdgcn_update_dpp(v, v, 0x111, 0xf, 0xf, false); // shr1
    const int s1b = __builtin_amdgcn_update_dpp(v, v, 0x112, 0xf, 0xf, false); // shr2
    const u32 t1 = umax3(g, (u32)s1a, (u32)s1b);                // window 3
    const int w = (int)t1;
    const int s2a = __builtin_amdgcn_update_dpp(w, w, 0x113, 0xf, 0xf, false); // shr3
    const int s2b = __builtin_amdgcn_update_dpp(w, w, 0x116, 0xf, 0xf, false); // shr6
    const u32 t2 = umax3(t1, (u32)s2a, (u32)s2b);               // window 9
    const int y = (int)t2;
    const int s3 = __builtin_amdgcn_update_dpp(y, y, 0x117, 0xf, 0xf, false);  // shr7
    const u32 t3 = umax2(t2, (u32)s3);                          // window 16
    const u32 a = (u32)__builtin_amdgcn_readlane((int)t3, 15);
    const u32 b = (u32)__builtin_amdgcn_readlane((int)t3, 31);
    const u32 c = (u32)__builtin_amdgcn_readlane((int)t3, 47);
    const u32 d = (u32)__builtin_amdgcn_readlane((int)t3, 63);
    return umax2(umax2(a, b), umax2(c, d));                     // scalar s_max
}

__device__ __forceinline__ u64 readlane_u64(u64 v, int lane) {
    unsigned lo = (unsigned)__builtin_amdgcn_readlane((int)(unsigned)v, lane);
    unsigned hi = (unsigned)__builtin_amdgcn_readlane((int)(v >> 32), lane);
    return ((u64)hi << 32) | lo;
}

// Self-identifying key: val[31:12] | (~row)[11:6] | (~col)[5:0].
// Wave max alone yields winner (row, col); ties resolve to smallest flat idx.
#define PK(f, c) ((sortable(f) & 0xFFFFF000u) | rowtag | (u32)(63 - (c)))
// LDS float4 -> four named packed registers.
#define LOADP(s, a, b, c, d) { const float4 v_ = row4[(s) ^ x]; \
    p##a = PK(v_.x, a); p##b = PK(v_.y, b); p##c = PK(v_.z, c); p##d = PK(v_.w, d); }

#define T1(n, A, B, C2) const u32 a##n = umax3(KM(A), KM(B), KM(C2));

// One block per batch. 4 waves stage pairmax into LDS; wave 0 holds its row as
// 64 packed u32 registers (loop-invariant) + a cumulative not-blocked mask and
// runs the greedy loop with ZERO memory ops; wave 1 does the label score.
__global__ __launch_bounds__(256)
__attribute__((amdgpu_waves_per_eu(1, 1)))
void tree_crf_mst_kernel(const float* __restrict__ le,   // [B, M, M, R]
                         const int* __restrict__ tree,   // [B, M, 3]
                         float* __restrict__ mst_out,    // [B]
                         float* __restrict__ ls_out)     // [B]
{
    __shared__ __align__(16) float pm[M * M];            // 16 KB swizzled rows
    const int b = blockIdx.x;
    const int tt = threadIdx.x;
    const float* bl = le + (size_t)b * M * M * R;
    const float4* g4 = reinterpret_cast<const float4*>(bl);

    // ---- stage pairmax[r][c] = max_k le[r,c,k] (all 4 waves, coalesced) ----
    for (int q = tt; q < M * M; q += 256) {
        const float4 a  = g4[2 * q];
        const float4 c4 = g4[2 * q + 1];
        const float mx = fmaxf(fmaxf(fmaxf(a.x, a.y), fmaxf(a.z, a.w)),
                               fmaxf(fmaxf(c4.x, c4.y), fmaxf(c4.z, c4.w)));
        const int rr = q >> 6, cc = q & 63;
        pm[PM_IDX(rr, cc)] = mx;
    }
    __syncthreads();                                     // only barrier

    const int wave = tt >> 6;
    const int t = tt & 63;

    if (wave == 1) {
        // ---- label tree score (overlaps wave 0's greedy loop) ----
        const int* tr = tree + ((size_t)b * M + t) * 3;
        const int i0 = tr[0], i1 = tr[1], i2 = tr[2];
        float ls = 0.0f;
        if (!((i0 == 0) & (i1 == 0) & (i2 == 0)))        // (0,0,0) contributes 0
            ls = bl[(size_t)((i0 << 6) | i1) * R + i2];
        #pragma unroll
        for (int off = 32; off; off >>= 1) ls += __shfl_down(ls, off);
        if (t == 0) ls_out[b] = ls;
        return;
    }
    if (wave != 0) return;

    // ---- lane t: row t as 64 packed u32 named registers (loop-invariant) ----
    u32 p0,p1,p2,p3,p4,p5,p6,p7,p8,p9,p10,p11,p12,p13,p14,p15,
        p16,p17,p18,p19,p20,p21,p22,p23,p24,p25,p26,p27,p28,p29,p30,p31,
        p32,p33,p34,p35,p36,p37,p38,p39,p40,p41,p42,p43,p44,p45,p46,p47,
        p48,p49,p50,p51,p52,p53,p54,p55,p56,p57,p58,p59,p60,p61,p62,p63;
    {
        const float4* row4 = reinterpret_cast<const float4*>(pm) + (t << 4);
        const int x = t & 7;
        const u32 rowtag = (u32)(63 - t) << 6;
        LOADP(0,  0,  1,  2,  3)  LOADP(1,  4,  5,  6,  7)
        LOADP(2,  8,  9,  10, 11) LOADP(3,  12, 13, 14, 15)
        LOADP(4,  16, 17, 18, 19) LOADP(5,  20, 21, 22, 23)
        LOADP(6,  24, 25, 26, 27) LOADP(7,  28, 29, 30, 31)
        LOADP(8,  32, 33, 34, 35) LOADP(9,  36, 37, 38, 39)
        LOADP(10, 40, 41, 42, 43) LOADP(11, 44, 45, 46, 47)
        LOADP(12, 48, 49, 50, 51) LOADP(13, 52, 53, 54, 55)
        LOADP(14, 56, 57, 58, 59) LOADP(15, 60, 61, 62, 63)
    }

    const u64 lanebit = 1ull << t;
    u64 mask = lanebit;                                  // partition of node t
    u32 nlo = 0xFFFFFFFFu, nhi = 0xFFFFFFFFu;            // ~blocked columns
    float mst = 0.0f;

    #pragma unroll 1                                     // keep loop rolled
    for (int it = 0; it < M; ++it) {
        // ---- masked row max: 2-op mask leaves + v_max3_u32 tree ----
        T1(0,0,1,2)    T1(1,3,4,5)    T1(2,6,7,8)    T1(3,9,10,11)
        T1(4,12,13,14) T1(5,15,16,17) T1(6,18,19,20) T1(7,21,22,23)
        T1(8,24,25,26) T1(9,27,28,29) T1(10,30,31,32) T1(11,33,34,35)
        T1(12,36,37,38) T1(13,39,40,41) T1(14,42,43,44) T1(15,45,46,47)
        T1(16,48,49,50) T1(17,51,52,53) T1(18,54,55,56) T1(19,57,58,59)
        T1(20,60,61,62)
        const u32 a21 = KM(63);
        const u32 b0 = umax3(a0,  a1,  a2);
        const u32 b1 = umax3(a3,  a4,  a5);
        const u32 b2 = umax3(a6,  a7,  a8);
        const u32 b3 = umax3(a9,  a10, a11);
        const u32 b4 = umax3(a12, a13, a14);
        const u32 b5 = umax3(a15, a16, a17);
        const u32 b6 = umax3(a18, a19, a20);
        const u32 c0 = umax3(b0, b1, b2);
        const u32 c1 = umax3(b3, b4, b5);
        const u32 c2 = umax2(b6, a21);
        const u32 rowmax = umax3(c0, c1, c2);

        // ---- global max: key alone identifies winner (row, col) ----
        const u32 gv = wave_umax_scalar(rowmax);         // uniform
        const int gi = 63 - (int)((gv >> 6) & 63u);      // winner row
        const int gj = 63 - (int)(gv & 63u);             // winner col
        const u64 mf = readlane_u64(mask, gi);
        const u64 mt = readlane_u64(mask, gj);

        mst += unsortable((gv & 0xFFFFF000u) | 0x800u);  // bucket midpoint

        const u64 merged = mf | mt;
        if (merged & lanebit) mask = merged;

        // ---- block P x Q and Q x P (row-t slice): cumulative bitmask only ----
        const u64 rb = ((mf & lanebit) ? mt : 0ull) | ((mt & lanebit) ? mf : 0ull);
        nlo &= ~(u32)rb;
        nhi &= ~(u32)(rb >> 32);
    }
    if (t == 0) mst_out[b] = mst;
}

// Fixed-order final reduction -> deterministic scalar output.
__global__ void tree_crf_reduce_kernel(const float* __restrict__ mst_p,
                                       const float* __restrict__ ls_p,
                                       float* __restrict__ out)
{
    if (threadIdx.x == 0 && blockIdx.x == 0) {
        float s = 0.0f;
        for (int i = 0; i < BATCH; ++i) s += mst_p[i] - ls_p[i];
        out[0] = s * (1.0f / BATCH);
    }
}

extern "C" void kernel_launch(void* const* d_in, const int* in_sizes, int n_in,
                              void* d_out, int out_size, void* d_ws, size_t ws_size,
                              hipStream_t stream) {
    const float* le   = (const float*)d_in[0];   // [32, 64, 64, 8] f32
    const int*   tree = (const int*)d_in[1];     // [32, 64, 3] i32
    float* out = (float*)d_out;                  // [1] f32
    float* mst_p = (float*)d_ws;                 // [32]
    float* ls_p  = mst_p + BATCH;                // [32]

    tree_crf_mst_kernel<<<BATCH, 256, 0, stream>>>(le, tree, mst_p, ls_p);
    tree_crf_reduce_kernel<<<1, 64, 0, stream>>>(mst_p, ls_p, out);
}

// Round 11
// 35.452 us; speedup vs baseline: 1.4643x; 1.2819x over previous
//
#include <hip/hip_runtime.h>
#include <math.h>

#define BATCH 32
#define M 64
#define R 8
typedef unsigned long long u64;
typedef unsigned int u32;

// XOR swizzle of the float4 slot within a 64-float (256 B) LDS row (G4 recipe).
#define SWZ_SLOT(r, s) ((s) ^ ((r) & 7))
#define PM_IDX(r, c) ((((r) << 6)) + ((SWZ_SLOT((r), (c) >> 2) << 2) | ((c) & 3)))

#define NSLOT 33   // 32 folded strict-lower slots + 1 diagonal slot per lane

__device__ __forceinline__ u32 umax2(u32 a, u32 b) { return a > b ? a : b; }
__device__ __forceinline__ u32 umax3(u32 a, u32 b, u32 c) {
    return umax2(umax2(a, b), c);                    // fuses to v_max3_u32
}

// Monotone f32 -> u32 map (order-preserving, total).
__device__ __forceinline__ u32 sortable(float f) {
    const u32 u = __float_as_uint(f);
    return u ^ ((u32)(((int)u) >> 31) | 0x80000000u);
}
// Inverse (low 12 bits unknown; caller passes bucket midpoint).
__device__ __forceinline__ float unsortable(u32 k) {
    const u32 fb = (k & 0x80000000u) ? (k ^ 0x80000000u) : ~k;
    return __uint_as_float(fb);
}

// sign-extended bit j of w: 0xFFFFFFFF if set, else 0 (v_bfe_i32).
#define SEXTBIT(w, j) ((u32)(((int)((w) << (31 - (j)))) >> 31))

// Wave-wide u32 max: 3 max3-windowed DPP steps (16-lane rows) + 4 readlanes
// + scalar max tree. old=src, bound_ctrl=false => invalid lanes self-max.
__device__ __forceinline__ u32 wave_umax_scalar(u32 g) {
    int v = (int)g;
    const int s1a = __builtin_amdgcn_update_dpp(v, v, 0x111, 0xf, 0xf, false); // shr1
    const int s1b = __builtin_amdgcn_update_dpp(v, v, 0x112, 0xf, 0xf, false); // shr2
    const u32 t1 = umax3(g, (u32)s1a, (u32)s1b);                // window 3
    const int w = (int)t1;
    const int s2a = __builtin_amdgcn_update_dpp(w, w, 0x113, 0xf, 0xf, false); // shr3
    const int s2b = __builtin_amdgcn_update_dpp(w, w, 0x116, 0xf, 0xf, false); // shr6
    const u32 t2 = umax3(t1, (u32)s2a, (u32)s2b);               // window 9
    const int y = (int)t2;
    const int s3 = __builtin_amdgcn_update_dpp(y, y, 0x117, 0xf, 0xf, false);  // shr7
    const u32 t3 = umax2(t2, (u32)s3);                          // window 16
    const u32 a = (u32)__builtin_amdgcn_readlane((int)t3, 15);
    const u32 b = (u32)__builtin_amdgcn_readlane((int)t3, 31);
    const u32 c = (u32)__builtin_amdgcn_readlane((int)t3, 47);
    const u32 d = (u32)__builtin_amdgcn_readlane((int)t3, 63);
    return umax2(umax2(a, b), umax2(c, d));                     // scalar s_max
}

__device__ __forceinline__ u64 readlane_u64(u64 v, int lane) {
    unsigned lo = (unsigned)__builtin_amdgcn_readlane((int)(unsigned)v, lane);
    unsigned hi = (unsigned)__builtin_amdgcn_readlane((int)(v >> 32), lane);
    return ((u64)hi << 32) | lo;
}

// masked main-slot leaf (slot j in 0..31, mask word cmb).
#define KM(j) (q##j & SEXTBIT(cmb, j))
#define T1G(n, A, B, C2) const u32 a##n = umax3(KM(A), KM(B), KM(C2));
#define LOADK(k) const u32 q##k = fold_lds[fbase + (k)];

// One block per batch. 4 waves: stage pairmax into LDS, barrier, pre-fold the
// lower triangle into per-lane key slots [64][33], barrier; then wave 0 runs
// the greedy loop on 33 register keys/lane (half the R10 work), wave 1 does
// the label score concurrently.
__global__ __launch_bounds__(256)
__attribute__((amdgpu_waves_per_eu(1, 1)))
void tree_crf_mst_kernel(const float* __restrict__ le,   // [B, M, M, R]
                         const int* __restrict__ tree,   // [B, M, 3]
                         float* __restrict__ mst_out,    // [B]
                         float* __restrict__ ls_out)     // [B]
{
    __shared__ __align__(16) float pm[M * M];            // 16 KB swizzled rows
    __shared__ u32 fold_lds[M * NSLOT];                  // 8.25 KB folded keys
    const int b = blockIdx.x;
    const int tt = threadIdx.x;
    const float* bl = le + (size_t)b * M * M * R;
    const float4* g4 = reinterpret_cast<const float4*>(bl);

    // ---- stage pairmax[r][c] = max_k le[r,c,k] (all 4 waves, coalesced) ----
    for (int q = tt; q < M * M; q += 256) {
        const float4 a  = g4[2 * q];
        const float4 c4 = g4[2 * q + 1];
        const float mx = fmaxf(fmaxf(fmaxf(a.x, a.y), fmaxf(a.z, a.w)),
                               fmaxf(fmaxf(c4.x, c4.y), fmaxf(c4.z, c4.w)));
        const int rr = q >> 6, cc = q & 63;
        pm[PM_IDX(rr, cc)] = mx;
    }
    __syncthreads();

    // ---- pre-fold: key{r,c} = max over both directions, self-identifying ----
    // lane layout: s=lane>>1; even: rowB=63-s cols 0..31; odd: rowB cols
    // 32..62-s then rowA=s cols 0..s-1; slot 32 = diagonal (lane,lane).
    for (int S = tt; S < M * NSLOT; S += 256) {
        const int k = S >> 6, lane = S & 63;
        const int s = lane >> 1, e = lane & 1;
        int r, c; bool valid = true;
        if (k == 32)      { r = lane; c = lane; }
        else if (!e)      { r = 63 - s; c = k; }
        else if (k <= 30 - s) { r = 63 - s; c = 32 + k; }
        else if (k <= 30) { r = s; c = k - (31 - s); }
        else              { r = 0; c = 0; valid = false; }
        u32 key = 0;
        if (valid) {
            const u32 v = umax2(sortable(pm[PM_IDX(r, c)]),
                                sortable(pm[PM_IDX(c, r)]));
            key = (v & 0xFFFFF000u) | ((u32)(63 - r) << 6) | (u32)(63 - c);
        }
        fold_lds[lane * NSLOT + k] = key;
    }
    __syncthreads();

    const int wave = tt >> 6;
    const int t = tt & 63;

    if (wave == 1) {
        // ---- label tree score (overlaps wave 0's greedy loop) ----
        const int* tr = tree + ((size_t)b * M + t) * 3;
        const int i0 = tr[0], i1 = tr[1], i2 = tr[2];
        float ls = 0.0f;
        if (!((i0 == 0) & (i1 == 0) & (i2 == 0)))        // (0,0,0) contributes 0
            ls = bl[(size_t)((i0 << 6) | i1) * R + i2];
        #pragma unroll
        for (int off = 32; off; off >>= 1) ls += __shfl_down(ls, off);
        if (t == 0) ls_out[b] = ls;
        return;
    }
    if (wave != 0) return;

    // ---- lane t: 33 folded keys as named registers (loop-invariant) ----
    const int fbase = t * NSLOT;
    LOADK(0)  LOADK(1)  LOADK(2)  LOADK(3)  LOADK(4)  LOADK(5)
    LOADK(6)  LOADK(7)  LOADK(8)  LOADK(9)  LOADK(10) LOADK(11)
    LOADK(12) LOADK(13) LOADK(14) LOADK(15) LOADK(16) LOADK(17)
    LOADK(18) LOADK(19) LOADK(20) LOADK(21) LOADK(22) LOADK(23)
    LOADK(24) LOADK(25) LOADK(26) LOADK(27) LOADK(28) LOADK(29)
    LOADK(30) LOADK(31) LOADK(32)

    const int s  = t >> 1;
    const int eO = t & 1;                                // odd-lane flag
    const int rB = 63 - s, rA = s;
    const int shA = 31 - s, shC = s + 1;
    const u64 lanebit = 1ull << t;

    u64 mask = lanebit;                                  // partition of node t
    u32 nBlo = 0xFFFFFFFFu, nBhi = 0xFFFFFFFFu;          // row B not-blocked
    u32 nA   = 0xFFFFFFFFu;                              // row A not-blocked (lo)
    u32 dm   = 0xFFFFFFFFu;                              // diagonal alive mask
    float mst = 0.0f;

    #pragma unroll 1                                     // keep loop rolled
    for (int it = 0; it < M; ++it) {
        // ---- per-slot not-blocked word for the 32 main slots ----
        const u32 cmbO = ((nBhi << shC) >> shC) | (nA << shA);
        const u32 cmb  = eO ? cmbO : nBlo;

        // ---- masked row max: 2-op leaves + v_max3_u32 tree ----
        T1G(0,0,1,2)    T1G(1,3,4,5)    T1G(2,6,7,8)    T1G(3,9,10,11)
        T1G(4,12,13,14) T1G(5,15,16,17) T1G(6,18,19,20) T1G(7,21,22,23)
        T1G(8,24,25,26) T1G(9,27,28,29)
        const u32 a10 = umax3(KM(30), KM(31), q32 & dm); // last pair + diagonal
        const u32 b0 = umax3(a0, a1, a2);
        const u32 b1 = umax3(a3, a4, a5);
        const u32 b2 = umax3(a6, a7, a8);
        const u32 b3 = umax2(a9, a10);
        const u32 rowmax = umax3(umax2(b0, b1), b2, b3);

        // ---- global max: key alone identifies winner pair {gi, gj} ----
        const u32 gv = wave_umax_scalar(rowmax);         // uniform
        const int gi = 63 - (int)((gv >> 6) & 63u);
        const int gj = 63 - (int)(gv & 63u);
        const u64 mf = readlane_u64(mask, gi);
        const u64 mt = readlane_u64(mask, gj);

        mst += unsortable((gv & 0xFFFFF000u) | 0x800u);  // bucket midpoint

        const u64 merged = mf | mt;
        if (merged & lanebit) mask = merged;

        // ---- update blocked state (row B, row A, diagonal) ----
        const u64 rbB = (((u32)(mf >> rB) & 1u) ? mt : 0ull) |
                        (((u32)(mt >> rB) & 1u) ? mf : 0ull);
        nBlo &= ~(u32)rbB;
        nBhi &= ~(u32)(rbB >> 32);
        const u32 rbA = (((u32)(mf >> rA) & 1u) ? (u32)mt : 0u) |
                        (((u32)(mt >> rA) & 1u) ? (u32)mf : 0u);
        nA &= ~rbA;
        dm &= ~(0u - ((u32)(mf >> t) & (u32)(mt >> t) & 1u));
    }
    if (t == 0) mst_out[b] = mst;
}

// Fixed-order final reduction -> deterministic scalar output.
__global__ void tree_crf_reduce_kernel(const float* __restrict__ mst_p,
                                       const float* __restrict__ ls_p,
                                       float* __restrict__ out)
{
    if (threadIdx.x == 0 && blockIdx.x == 0) {
        float s = 0.0f;
        for (int i = 0; i < BATCH; ++i) s += mst_p[i] - ls_p[i];
        out[0] = s * (1.0f / BATCH);
    }
}

extern "C" void kernel_launch(void* const* d_in, const int* in_sizes, int n_in,
                              void* d_out, int out_size, void* d_ws, size_t ws_size,
                              hipStream_t stream) {
    const float* le   = (const float*)d_in[0];   // [32, 64, 64, 8] f32
    const int*   tree = (const int*)d_in[1];     // [32, 64, 3] i32
    float* out = (float*)d_out;                  // [1] f32
    float* mst_p = (float*)d_ws;                 // [32]
    float* ls_p  = mst_p + BATCH;                // [32]

    tree_crf_mst_kernel<<<BATCH, 256, 0, stream>>>(le, tree, mst_p, ls_p);
    tree_crf_reduce_kernel<<<1, 64, 0, stream>>>(mst_p, ls_p, out);
}